// Round 15
// baseline (1879.706 us; speedup 1.0000x reference)
//
#include <hip/hip_runtime.h>

#define NN 32768
#define DD 1024
#define RR 256
#define KK 8192

typedef float f32x4 __attribute__((ext_vector_type(4)));
typedef _Float16 half8 __attribute__((ext_vector_type(8)));
typedef _Float16 half4_t __attribute__((ext_vector_type(4)));

// d_out layout (floats): [loss, rec, z(N*R), q(N*R), idx(N)]
#define OFF_Z   2L
#define OFF_Q   (2L + (long)NN * RR)
#define OFF_IDX (2L + 2L * (long)NN * RR)

// workspace layout (bytes)
#define O_WT   0L          // f16 W^T [1024][256] : 512 KB
#define O_CF   524288L     // f16 code, FRAGMENT-SWIZZLED [512 tiles][8 ks][64 lanes][8] : 4 MB
#define O_CN   4718592L    // f32 ||c||^2 fp32-fast [8192] : 32 KB
#define O_A    4751360L    // f32 np-replica sum(z*z) [32768] : 128 KB
#define O_B    4882432L    // f32 np-replica sum(c*c) [8192]  : 32 KB
#define O_M1   4915200L    // f32 fp16-path min value [32768] : 128 KB
#define O_KEY  5046272L    // u64 packed (d2bits<<13|idx) [32768] : 256 KB
#define O_CNT  5308416L    // int listcnt; int flagcnt; float recsum; float cbsum
#define O_FLAG 5308432L    // int flagged rows [16384] : 64 KB
#define O_LIST 5373952L    // u32 (row<<13|cand) entries : 1 MB
#define LIST_CAP 262144
#define FCAP 16384

// Margins: fp16-path s-error sigma ~1e-3. Rows with fp16 gap (m2-m1) < TAU
// are rescored in np-fp32; unflagged rows have true gap > TAU - 2*8sigma
// = 0.009 >> np-fp32 noise (~1e-4), so the fp16 argmin IS the np argmin.
#define TAU_S 0.025f

// ---------- K0: W^T as f16 (for decode GEMM) ----------
__global__ void k_wt(const float* __restrict__ W, _Float16* __restrict__ Wt) {
  __shared__ float tile[64][65];
  int d0 = blockIdx.x * 64, r0 = blockIdx.y * 64;
  int t = threadIdx.x;
#pragma unroll
  for (int it = 0; it < 16; ++it) {
    int i = t + it * 256;
    int r = i >> 6, d = i & 63;
    tile[r][d] = W[(long)(r0 + r) * DD + d0 + d];
  }
  __syncthreads();
#pragma unroll
  for (int it = 0; it < 16; ++it) {
    int i = t + it * 256;
    int d = i >> 6, r = i & 63;
    Wt[(long)(d0 + d) * RR + r0 + r] = (_Float16)tile[r][d];
  }
}

// ---------- K0: code -> f16 fragment-swizzled + fast ||c||^2 ----------
__global__ void k_code(const float* __restrict__ code, _Float16* __restrict__ cfs,
                       float* __restrict__ cnorm) {
  int k = blockIdx.x;
  int l = threadIdx.x;                                // 64 threads
  f32x4 v = ((const f32x4*)code)[(long)k * 64 + l];
  half4_t h;
#pragma unroll
  for (int j = 0; j < 4; ++j) h[j] = (_Float16)v[j];
  long dst = ((long)(k >> 4) << 12) + ((long)(l >> 3) << 9) +
             (((l >> 1) & 3) << 7) + ((k & 15) << 3) + ((l & 1) << 2);
  *(half4_t*)(cfs + dst) = h;
  float s = v[0]*v[0] + v[1]*v[1] + v[2]*v[2] + v[3]*v[3];
#pragma unroll
  for (int off = 1; off < 64; off <<= 1) s += __shfl_xor(s, off);
  if (l == 0) cnorm[k] = s;
}

// ---------- K1: np-replica z = einsum('nd,rd->nr') in numpy SSE1 order ----------
// v6: W staged in LDS (r10 pattern, coalesced, bank-clean); x read via the
// SCALAR pipe — base pointer forced wave-uniform with readfirstlane so the
// compiler emits s_load_dwordx4 (x addresses depend only on wave id). This
// takes the 8 per-g x reads off BOTH the LDS pipe (r10's limiter, 10 b128/g)
// and the vector-TA pipe (r14's limiter, 10 VMEM/g). Per g now: 2 ds_read
// + 8 s_load + 128 VALU-cyc -> VALU-bound. Arithmetic bit-identical: f32x4
// SSE accumulator, ascending-g mul-then-add, (s0+s1)+(s2+s3).
__global__ __launch_bounds__(256, 4)
void k_npz(const float* __restrict__ x, const float* __restrict__ W,
           float* __restrict__ z) {
#pragma clang fp contract(off)
  __shared__ float wsl[128][65];     // W[rh..rh+128, kchunk] padded
  int nb = blockIdx.x * 32;
  int rh = blockIdx.y * 128;
  int t = threadIdx.x;
  int rp = t & 63;
  int nh = t >> 6;

  // wave-uniform x base (nh is constant within a wave) -> SGPR pointer
  unsigned long long xa =
      (unsigned long long)(uintptr_t)(x + (long)(nb + nh * 8) * DD);
  unsigned xlo = __builtin_amdgcn_readfirstlane((unsigned)xa);
  unsigned xhi = __builtin_amdgcn_readfirstlane((unsigned)(xa >> 32));
  const float* xu =
      (const float*)(uintptr_t)(((unsigned long long)xhi << 32) | xlo);

  f32x4 acc[8][2];
#pragma unroll
  for (int n = 0; n < 8; ++n) {
    acc[n][0] = (f32x4){0.f, 0.f, 0.f, 0.f};
    acc[n][1] = (f32x4){0.f, 0.f, 0.f, 0.f};
  }

  for (int ch = 0; ch < 16; ++ch) {
    __syncthreads();
    // stage W[rh..rh+128, ch*64 .. +64): 2048 f32x4, 8 per thread
#pragma unroll
    for (int it = 0; it < 8; ++it) {
      int idx = t + it * 256;
      int r = idx >> 4, kk = (idx & 15) << 2;
      *(f32x4*)&wsl[r][kk] = *(const f32x4*)(W + (long)(rh + r) * DD + ch * 64 + kk);
    }
    __syncthreads();
#pragma unroll 4
    for (int g = 0; g < 16; ++g) {
      f32x4 w0 = *(const f32x4*)&wsl[rp][g * 4];
      f32x4 w1 = *(const f32x4*)&wsl[rp + 64][g * 4];
#pragma unroll
      for (int n = 0; n < 8; ++n) {
        f32x4 xv = *(const f32x4*)(xu + n * DD + ch * 64 + g * 4); // s_load
        f32x4 p0 = xv * w0;               // v_mul (no fma: contract off)
        acc[n][0] = acc[n][0] + p0;       // v_add
        f32x4 p1 = xv * w1;
        acc[n][1] = acc[n][1] + p1;
      }
    }
  }
#pragma unroll
  for (int n = 0; n < 8; ++n)
#pragma unroll
    for (int q = 0; q < 2; ++q) {
      float sa = acc[n][q][0] + acc[n][q][1];
      float sb = acc[n][q][2] + acc[n][q][3];
      z[(long)(nb + nh * 8 + n) * RR + rh + rp + q * 64] = sa + sb;
    }
}

// ---------- np-replica pairwise sum of squares over 256 ----------
__device__ __forceinline__ float np_pw256_sq(const float* __restrict__ p) {
#pragma clang fp contract(off)
  float blk[2];
#pragma unroll
  for (int h = 0; h < 2; ++h) {
    const float* q = p + h * 128;
    float r[8];
#pragma unroll
    for (int j = 0; j < 8; ++j) { float v = q[j]; r[j] = v * v; }
    for (int i = 8; i < 128; i += 8) {
#pragma unroll
      for (int j = 0; j < 8; ++j) { float v = q[i + j]; r[j] = r[j] + v * v; }
    }
    float ta = r[0] + r[1], tb = r[2] + r[3], tc = r[4] + r[5], td = r[6] + r[7];
    blk[h] = (ta + tb) + (tc + td);
  }
  return blk[0] + blk[1];
}

__global__ void k_sumA(const float* __restrict__ z, float* __restrict__ A) {
  int n = blockIdx.x * 256 + threadIdx.x;
  A[n] = np_pw256_sq(z + (long)n * RR);
}

__global__ void k_sumB(const float* __restrict__ code, float* __restrict__ B) {
  int k = blockIdx.x * 256 + threadIdx.x;
  B[k] = np_pw256_sq(code + (long)k * RR);
}

// ---------- K2a: fp16 MFMA single pass — m1, m2, argmin idx per row ----------
__global__ __launch_bounds__(256, 2)
void k_argmin(const float* __restrict__ z, const _Float16* __restrict__ cfs,
              const float* __restrict__ cnorm, float* __restrict__ m1arr,
              float* __restrict__ idxf, int* __restrict__ flagcnt,
              int* __restrict__ flags, int fcap) {
  __shared__ float sm1[4][64], sm2[4][64], si1[4][64];
  int n0 = blockIdx.x * 64;
  int tid = threadIdx.x;
  int l = tid & 63, w = tid >> 6;       // w = col-group 0..3
  int lr = l & 15, lg = l >> 4;

  half8 za[4][8];
#pragma unroll
  for (int rf = 0; rf < 4; ++rf) {
    const float* p = z + (long)(n0 + rf * 16 + lr) * RR + lg * 8;
#pragma unroll
    for (int ks = 0; ks < 8; ++ks) {
      f32x4 v0 = *(const f32x4*)(p + ks * 32);
      f32x4 v1 = *(const f32x4*)(p + ks * 32 + 4);
#pragma unroll
      for (int j = 0; j < 4; ++j) {
        za[rf][ks][j]     = (_Float16)v0[j];
        za[rf][ks][4 + j] = (_Float16)v1[j];
      }
    }
  }

  float m1[16], m2[16], i1[16];
#pragma unroll
  for (int s = 0; s < 16; ++s) { m1[s] = 3.4e38f; m2[s] = 3.4e38f; i1[s] = 0.f; }
  f32x4 zero = {0.f, 0.f, 0.f, 0.f};

  for (int ct = 0; ct < 128; ++ct) {
    int col0 = ct * 64 + w * 16;
    int c16 = ct * 4 + w;
    const _Float16* bp = cfs + ((long)c16 << 12) + (l << 3);
    float cn = cnorm[col0 + lr];
    float fi = (float)(col0 + lr);
    f32x4 a[4];
#pragma unroll
    for (int rf = 0; rf < 4; ++rf) a[rf] = zero;
#pragma unroll
    for (int ks = 0; ks < 8; ++ks) {
      half8 b = *(const half8*)(bp + ((long)ks << 9));
#pragma unroll
      for (int rf = 0; rf < 4; ++rf)
        a[rf] = __builtin_amdgcn_mfma_f32_16x16x32_f16(za[rf][ks], b, a[rf], 0, 0, 0);
    }
#pragma unroll
    for (int rf = 0; rf < 4; ++rf)
#pragma unroll
      for (int j = 0; j < 4; ++j) {
        int sl = rf * 4 + j;
        float s = fmaf(-2.f, a[rf][j], cn);
        float om1 = m1[sl];
        m2[sl] = fminf(m2[sl], fmaxf(s, om1));
        bool lt = s < om1;
        m1[sl] = lt ? s : om1;
        i1[sl] = lt ? fi : i1[sl];
      }
  }

  // 16-lane (candidate) reduce with first-index tie-break
#pragma unroll
  for (int sl = 0; sl < 16; ++sl) {
    float a1 = m1[sl], a2 = m2[sl], ai = i1[sl];
#pragma unroll
    for (int off = 1; off < 16; off <<= 1) {
      float b1 = __shfl_xor(a1, off);
      float b2 = __shfl_xor(a2, off);
      float bi = __shfl_xor(ai, off);
      float nm2 = fminf(fminf(a2, b2), fmaxf(a1, b1));
      bool take = (b1 < a1) || ((b1 == a1) && (bi < ai));
      a1 = take ? b1 : a1;
      ai = take ? bi : ai;
      a2 = nm2;
    }
    if (lr == 0) {
      int lrow = (sl >> 2) * 16 + lg * 4 + (sl & 3);
      sm1[w][lrow] = a1; sm2[w][lrow] = a2; si1[w][lrow] = ai;
    }
  }
  __syncthreads();
  if (tid < 64) {
    float a1 = sm1[0][tid], a2 = sm2[0][tid], ai = si1[0][tid];
#pragma unroll
    for (int ww = 1; ww < 4; ++ww) {
      float b1 = sm1[ww][tid], b2 = sm2[ww][tid], bi = si1[ww][tid];
      float nm2 = fminf(fminf(a2, b2), fmaxf(a1, b1));
      bool take = (b1 < a1) || ((b1 == a1) && (bi < ai));
      a1 = take ? b1 : a1;
      ai = take ? bi : ai;
      a2 = nm2;
    }
    int row = n0 + tid;
    idxf[row] = ai;
    m1arr[row] = a1;
    if (a2 - a1 < TAU_S) {
      int p = atomicAdd(flagcnt, 1);
      if (p < fcap) flags[p] = row;
    }
  }
}

// ---------- K2b: collect — FLAGGED ROWS ONLY, all candidates within TAU ----------
__global__ __launch_bounds__(256, 2)
void k_collect(const float* __restrict__ z, const _Float16* __restrict__ cfs,
               const float* __restrict__ cnorm, const float* __restrict__ m1arr,
               const int* __restrict__ flagcnt, const int* __restrict__ flags,
               int fcap, int* __restrict__ listcnt, unsigned* __restrict__ list,
               int cap) {
  int n = *flagcnt; if (n > fcap) n = fcap;
  int n0 = blockIdx.x * 64;
  if (n0 >= n) return;
  int tid = threadIdx.x;
  int l = tid & 63, w = tid >> 6;
  int lr = l & 15, lg = l >> 4;

  half8 za[4][8];
#pragma unroll
  for (int rf = 0; rf < 4; ++rf) {
    int fidx = n0 + rf * 16 + lr;
    int zrow = (fidx < n) ? flags[fidx] : 0;
    const float* p = z + (long)zrow * RR + lg * 8;
#pragma unroll
    for (int ks = 0; ks < 8; ++ks) {
      f32x4 v0 = *(const f32x4*)(p + ks * 32);
      f32x4 v1 = *(const f32x4*)(p + ks * 32 + 4);
#pragma unroll
      for (int j = 0; j < 4; ++j) {
        za[rf][ks][j]     = (_Float16)v0[j];
        za[rf][ks][4 + j] = (_Float16)v1[j];
      }
    }
  }

  unsigned rows[16];
  float thr[16];
#pragma unroll
  for (int sl = 0; sl < 16; ++sl) {
    int fidx = n0 + (sl >> 2) * 16 + lg * 4 + (sl & 3);
    bool v = fidx < n;
    rows[sl] = v ? (unsigned)flags[fidx] : 0u;
    thr[sl] = v ? m1arr[rows[sl]] + TAU_S : -3.4e38f;
  }
  f32x4 zero = {0.f, 0.f, 0.f, 0.f};

  for (int ct = 0; ct < 128; ++ct) {
    int col0 = ct * 64 + w * 16;
    int c16 = ct * 4 + w;
    const _Float16* bp = cfs + ((long)c16 << 12) + (l << 3);
    float cn = cnorm[col0 + lr];
    unsigned cand = (unsigned)(col0 + lr);
    f32x4 a[4];
#pragma unroll
    for (int rf = 0; rf < 4; ++rf) a[rf] = zero;
#pragma unroll
    for (int ks = 0; ks < 8; ++ks) {
      half8 b = *(const half8*)(bp + ((long)ks << 9));
#pragma unroll
      for (int rf = 0; rf < 4; ++rf)
        a[rf] = __builtin_amdgcn_mfma_f32_16x16x32_f16(za[rf][ks], b, a[rf], 0, 0, 0);
    }
#pragma unroll
    for (int rf = 0; rf < 4; ++rf)
#pragma unroll
      for (int j = 0; j < 4; ++j) {
        int sl = rf * 4 + j;
        float s = fmaf(-2.f, a[rf][j], cn);
        if (s < thr[sl]) {
          int pos = atomicAdd(listcnt, 1);
          if (pos < cap) list[pos] = (rows[sl] << 13) | cand;
        }
      }
  }
}

// ---------- K2c: np-replica d2 for shortlist; packed-key argmin ----------
__global__ void k_npd2(const float* __restrict__ z, const float* __restrict__ code,
                       const float* __restrict__ A, const float* __restrict__ B,
                       const int* __restrict__ listcnt, const unsigned* __restrict__ list,
                       unsigned long long* __restrict__ keys, int cap) {
#pragma clang fp contract(off)
  int n = *listcnt; if (n > cap) n = cap;
  for (int i = blockIdx.x * 256 + threadIdx.x; i < n; i += gridDim.x * 256) {
    unsigned e = list[i];
    int row = (int)(e >> 13), k = (int)(e & 8191u);
    const float* zp = z + (long)row * RR;
    const float* cp = code + (long)k * RR;
    float s0 = 0.f, s1 = 0.f, s2 = 0.f, s3 = 0.f;
    for (int g = 0; g < 64; ++g) {
      f32x4 zv = *(const f32x4*)(zp + g * 4);
      f32x4 cv = *(const f32x4*)(cp + g * 4);
      s0 = s0 + zv[0] * cv[0];
      s1 = s1 + zv[1] * cv[1];
      s2 = s2 + zv[2] * cv[2];
      s3 = s3 + zv[3] * cv[3];
    }
    float C = (s0 + s1) + (s2 + s3);
    float t1 = A[row] + B[k];
    float d2 = t1 - 2.0f * C;
    unsigned long long key = ((unsigned long long)__float_as_uint(d2) << 13) |
                             (unsigned long long)(unsigned)k;
    atomicMin(&keys[row], key);
  }
}

// ---------- K2d: overwrite idx for flagged rows from np-fp32 keys ----------
__global__ void k_fix(const int* __restrict__ flagcnt, const int* __restrict__ flags,
                      const unsigned long long* __restrict__ keys,
                      float* __restrict__ idxf, int fcap) {
  int n = *flagcnt; if (n > fcap) n = fcap;
  for (int i = blockIdx.x * 256 + threadIdx.x; i < n; i += gridDim.x * 256) {
    int row = flags[i];
    unsigned long long k = keys[row];
    if (k != ~0ULL) idxf[row] = (float)(unsigned)(k & 8191ULL);
  }
}

// ---------- K3a: q = code[idx], cb partial sums ----------
__global__ void k_gather(const float* __restrict__ code, const float* __restrict__ z,
                         const float* __restrict__ idxf, float* __restrict__ q,
                         float* __restrict__ cbsum) {
  int t = threadIdx.x;
  int rid = blockIdx.x * 4 + (t >> 6);
  int l = t & 63;
  int k = (int)idxf[rid];
  f32x4 cv = ((const f32x4*)code)[(long)k * 64 + l];
  f32x4 zv = ((const f32x4*)z)[(long)rid * 64 + l];
  ((f32x4*)q)[(long)rid * 64 + l] = cv;
  f32x4 d = cv - zv;
  float s = d[0]*d[0] + d[1]*d[1] + d[2]*d[2] + d[3]*d[3];
#pragma unroll
  for (int off = 1; off < 64; off <<= 1) s += __shfl_xor(s, off);
  __shared__ float sw[4];
  if (l == 0) sw[t >> 6] = s;
  __syncthreads();
  if (t == 0) atomicAdd(cbsum, sw[0] + sw[1] + sw[2] + sw[3]);
}

// ---------- K3b: rec = mean((q@W - x)^2), fused fp16 MFMA + reduction ----------
__global__ __launch_bounds__(512, 2)
void k_rec(const float* __restrict__ q, const _Float16* __restrict__ Wt,
           const float* __restrict__ x, float* __restrict__ recsum) {
  int n0 = blockIdx.x * 128;
  int d0 = blockIdx.y * 512;
  int tid = threadIdx.x;
  int l = tid & 63, w = tid >> 6;
  int wr = w >> 2, wc = w & 3;
  int lr = l & 15, lg = l >> 4;
  f32x4 zero = {0.f, 0.f, 0.f, 0.f};
  f32x4 acc[4][8];
#pragma unroll
  for (int a = 0; a < 4; ++a)
#pragma unroll
    for (int b = 0; b < 8; ++b) acc[a][b] = zero;

  for (int kk = 0; kk < 8; ++kk) {
    half8 aq[4];
#pragma unroll
    for (int rf = 0; rf < 4; ++rf) {
      const float* p = q + (long)(n0 + wr * 64 + rf * 16 + lr) * RR + kk * 32 + lg * 8;
      f32x4 v0 = *(const f32x4*)p;
      f32x4 v1 = *(const f32x4*)(p + 4);
#pragma unroll
      for (int j = 0; j < 4; ++j) {
        aq[rf][j]     = (_Float16)v0[j];
        aq[rf][4 + j] = (_Float16)v1[j];
      }
    }
#pragma unroll
    for (int cfg = 0; cfg < 8; ++cfg) {
      const _Float16* bp = Wt + (long)(d0 + wc * 128 + cfg * 16 + lr) * RR + kk * 32 + lg * 8;
      half8 b = *(const half8*)bp;
#pragma unroll
      for (int rf = 0; rf < 4; ++rf)
        acc[rf][cfg] = __builtin_amdgcn_mfma_f32_16x16x32_f16(aq[rf], b, acc[rf][cfg], 0, 0, 0);
    }
  }
  float s = 0.f;
#pragma unroll
  for (int rf = 0; rf < 4; ++rf)
#pragma unroll
    for (int cfg = 0; cfg < 8; ++cfg)
#pragma unroll
      for (int j = 0; j < 4; ++j) {
        int n = n0 + wr * 64 + rf * 16 + lg * 4 + j;
        int d = d0 + wc * 128 + cfg * 16 + lr;
        float df = acc[rf][cfg][j] - x[(long)n * DD + d];
        s = fmaf(df, df, s);
      }
#pragma unroll
  for (int off = 1; off < 64; off <<= 1) s += __shfl_xor(s, off);
  __shared__ float sw[8];
  if (l == 0) sw[w] = s;
  __syncthreads();
  if (tid == 0) {
    float t8 = 0.f;
#pragma unroll
    for (int i = 0; i < 8; ++i) t8 += sw[i];
    atomicAdd(recsum, t8);
  }
}

// ---------- K3c: scalars ----------
__global__ void k_final(const float* __restrict__ rs, const float* __restrict__ cbs,
                        float* __restrict__ out) {
  if (threadIdx.x == 0 && blockIdx.x == 0) {
    float rec = *rs * (1.0f / 33554432.0f);   // / (N*D)
    float cb  = *cbs * (1.0f / 8388608.0f);   // / (N*R)
    out[0] = rec + 1.25f * cb;                // rec + cb + BETA*cb
    out[1] = rec;
  }
}

extern "C" void kernel_launch(void* const* d_in, const int* in_sizes, int n_in,
                              void* d_out, int out_size, void* d_ws, size_t ws_size,
                              hipStream_t stream) {
  (void)in_sizes; (void)n_in; (void)out_size; (void)ws_size;
  const float* x    = (const float*)d_in[0];
  const float* W    = (const float*)d_in[1];
  const float* code = (const float*)d_in[2];
  float* out = (float*)d_out;
  char* ws = (char*)d_ws;

  _Float16* Wt = (_Float16*)(ws + O_WT);
  _Float16* cfs = (_Float16*)(ws + O_CF);
  float* cnorm = (float*)(ws + O_CN);
  float* A = (float*)(ws + O_A);
  float* B = (float*)(ws + O_B);
  float* m1arr = (float*)(ws + O_M1);
  unsigned long long* keys = (unsigned long long*)(ws + O_KEY);
  int* listcnt = (int*)(ws + O_CNT);
  int* flagcnt = (int*)(ws + O_CNT + 4);
  float* recsum = (float*)(ws + O_CNT + 8);
  float* cbsum  = (float*)(ws + O_CNT + 12);
  int* flags = (int*)(ws + O_FLAG);
  unsigned* list = (unsigned*)(ws + O_LIST);

  float* zp = out + OFF_Z;
  float* qp = out + OFF_Q;
  float* ip = out + OFF_IDX;

  hipMemsetAsync(ws + O_CNT, 0, 16, stream);
  hipMemsetAsync(ws + O_KEY, 0xFF, (size_t)NN * 8, stream);

  k_wt<<<dim3(16, 4), dim3(256), 0, stream>>>(W, Wt);
  k_code<<<dim3(KK), dim3(64), 0, stream>>>(code, cfs, cnorm);
  k_npz<<<dim3(1024, 2), dim3(256), 0, stream>>>(x, W, zp);
  k_sumA<<<dim3(128), dim3(256), 0, stream>>>(zp, A);
  k_sumB<<<dim3(32), dim3(256), 0, stream>>>(code, B);
  k_argmin<<<dim3(512), dim3(256), 0, stream>>>(zp, cfs, cnorm, m1arr, ip, flagcnt, flags, FCAP);
  k_collect<<<dim3(FCAP / 64), dim3(256), 0, stream>>>(zp, cfs, cnorm, m1arr, flagcnt, flags, FCAP, listcnt, list, LIST_CAP);
  k_npd2<<<dim3(256), dim3(256), 0, stream>>>(zp, code, A, B, listcnt, list, keys, LIST_CAP);
  k_fix<<<dim3(64), dim3(256), 0, stream>>>(flagcnt, flags, keys, ip, FCAP);
  k_gather<<<dim3(8192), dim3(256), 0, stream>>>(code, zp, ip, qp, cbsum);
  k_rec<<<dim3(256, 2), dim3(512), 0, stream>>>(qp, Wt, x, recsum);
  k_final<<<dim3(1), dim3(64), 0, stream>>>(recsum, cbsum, out);
}

// Round 16
// 972.558 us; speedup vs baseline: 1.9327x; 1.9327x over previous
//
#include <hip/hip_runtime.h>

#define NN 32768
#define DD 1024
#define RR 256
#define KK 8192

typedef float f32x4 __attribute__((ext_vector_type(4)));
typedef _Float16 half8 __attribute__((ext_vector_type(8)));
typedef _Float16 half4_t __attribute__((ext_vector_type(4)));

// d_out layout (floats): [loss, rec, z(N*R), q(N*R), idx(N)]
#define OFF_Z   2L
#define OFF_Q   (2L + (long)NN * RR)
#define OFF_IDX (2L + 2L * (long)NN * RR)

// workspace layout (bytes)
#define O_WT   0L          // f16 W^T [1024][256] : 512 KB
#define O_CF   524288L     // f16 code, FRAGMENT-SWIZZLED [512 tiles][8 ks][64 lanes][8] : 4 MB
#define O_CN   4718592L    // f32 ||c||^2 fp32-fast [8192] : 32 KB
#define O_A    4751360L    // f32 np-replica sum(z*z) [32768] : 128 KB
#define O_B    4882432L    // f32 np-replica sum(c*c) [8192]  : 32 KB
#define O_M1   4915200L    // f32 fp16-path min value [32768] : 128 KB
#define O_KEY  5046272L    // u64 packed (d2bits<<13|idx) [32768] : 256 KB
#define O_CNT  5308416L    // int listcnt; int flagcnt; float recsum; float cbsum
#define O_FLAG 5308432L    // int flagged rows [16384] : 64 KB
#define O_LIST 5373952L    // u32 (row<<13|cand) entries : 1 MB
#define LIST_CAP 262144
#define FCAP 16384

// Margins: fp16-path s-error sigma ~1e-3. Rows with fp16 gap (m2-m1) < TAU
// are rescored in np-fp32; unflagged rows have true gap > TAU - 2*8sigma
// = 0.009 >> np-fp32 noise (~1e-4), so the fp16 argmin IS the np argmin.
#define TAU_S 0.025f

// ---------- K0: W^T as f16 (for decode GEMM) ----------
__global__ void k_wt(const float* __restrict__ W, _Float16* __restrict__ Wt) {
  __shared__ float tile[64][65];
  int d0 = blockIdx.x * 64, r0 = blockIdx.y * 64;
  int t = threadIdx.x;
#pragma unroll
  for (int it = 0; it < 16; ++it) {
    int i = t + it * 256;
    int r = i >> 6, d = i & 63;
    tile[r][d] = W[(long)(r0 + r) * DD + d0 + d];
  }
  __syncthreads();
#pragma unroll
  for (int it = 0; it < 16; ++it) {
    int i = t + it * 256;
    int d = i >> 6, r = i & 63;
    Wt[(long)(d0 + d) * RR + r0 + r] = (_Float16)tile[r][d];
  }
}

// ---------- K0: code -> f16 fragment-swizzled + fast ||c||^2 ----------
__global__ void k_code(const float* __restrict__ code, _Float16* __restrict__ cfs,
                       float* __restrict__ cnorm) {
  int k = blockIdx.x;
  int l = threadIdx.x;                                // 64 threads
  f32x4 v = ((const f32x4*)code)[(long)k * 64 + l];
  half4_t h;
#pragma unroll
  for (int j = 0; j < 4; ++j) h[j] = (_Float16)v[j];
  long dst = ((long)(k >> 4) << 12) + ((long)(l >> 3) << 9) +
             (((l >> 1) & 3) << 7) + ((k & 15) << 3) + ((l & 1) << 2);
  *(half4_t*)(cfs + dst) = h;
  float s = v[0]*v[0] + v[1]*v[1] + v[2]*v[2] + v[3]*v[3];
#pragma unroll
  for (int off = 1; off < 64; off <<= 1) s += __shfl_xor(s, off);
  if (l == 0) cnorm[k] = s;
}

// ---------- K1: np-replica z = einsum('nd,rd->nr') in numpy SSE1 order ----------
// r10 version VERBATIM — 422 us. Three attempts to beat it (global-x r11,
// zero-LDS r14, scalar-x r15) all regressed; this is npz's practical floor.
__global__ __launch_bounds__(256, 3)
void k_npz(const float* __restrict__ x, const float* __restrict__ W,
           float* __restrict__ z) {
#pragma clang fp contract(off)
  __shared__ float wsl[128][65];     // W[rh..rh+128, kchunk] padded
  __shared__ float xsl[32][64];      // x[ntile, kchunk]
  int nb = blockIdx.x * 32;
  int rh = blockIdx.y * 128;
  int t = threadIdx.x;
  int rp = t & 63;
  int nh = t >> 6;
  f32x4 acc[8][2];
#pragma unroll
  for (int n = 0; n < 8; ++n)
#pragma unroll
    for (int q = 0; q < 2; ++q) acc[n][q] = (f32x4){0.f, 0.f, 0.f, 0.f};

  for (int ch = 0; ch < 16; ++ch) {
    __syncthreads();
#pragma unroll
    for (int it = 0; it < 8; ++it) {
      int idx = t + it * 256;
      int r = idx >> 4, kk = (idx & 15) << 2;
      *(f32x4*)&wsl[r][kk] = *(const f32x4*)(W + (long)(rh + r) * DD + ch * 64 + kk);
    }
#pragma unroll
    for (int it = 0; it < 2; ++it) {
      int idx = t + it * 256;
      int r = idx >> 4, kk = (idx & 15) << 2;
      *(f32x4*)&xsl[r][kk] = *(const f32x4*)(x + (long)(nb + r) * DD + ch * 64 + kk);
    }
    __syncthreads();
#pragma unroll 4
    for (int g = 0; g < 16; ++g) {
      f32x4 w0 = *(const f32x4*)&wsl[rp][g * 4];
      f32x4 w1 = *(const f32x4*)&wsl[rp + 64][g * 4];
#pragma unroll
      for (int n = 0; n < 8; ++n) {
        f32x4 xv = *(const f32x4*)&xsl[nh * 8 + n][g * 4];
        f32x4 p0 = xv * w0;               // v_mul (no fma: contract off)
        acc[n][0] = acc[n][0] + p0;       // v_add
        f32x4 p1 = xv * w1;
        acc[n][1] = acc[n][1] + p1;
      }
    }
  }
#pragma unroll
  for (int n = 0; n < 8; ++n)
#pragma unroll
    for (int q = 0; q < 2; ++q) {
      float sa = acc[n][q][0] + acc[n][q][1];
      float sb = acc[n][q][2] + acc[n][q][3];
      z[(long)(nb + nh * 8 + n) * RR + rh + rp + q * 64] = sa + sb;
    }
}

// ---------- np-replica pairwise sum of squares over 256 ----------
__device__ __forceinline__ float np_pw256_sq(const float* __restrict__ p) {
#pragma clang fp contract(off)
  float blk[2];
#pragma unroll
  for (int h = 0; h < 2; ++h) {
    const float* q = p + h * 128;
    float r[8];
#pragma unroll
    for (int j = 0; j < 8; ++j) { float v = q[j]; r[j] = v * v; }
    for (int i = 8; i < 128; i += 8) {
#pragma unroll
      for (int j = 0; j < 8; ++j) { float v = q[i + j]; r[j] = r[j] + v * v; }
    }
    float ta = r[0] + r[1], tb = r[2] + r[3], tc = r[4] + r[5], td = r[6] + r[7];
    blk[h] = (ta + tb) + (tc + td);
  }
  return blk[0] + blk[1];
}

__global__ void k_sumA(const float* __restrict__ z, float* __restrict__ A) {
  int n = blockIdx.x * 256 + threadIdx.x;
  A[n] = np_pw256_sq(z + (long)n * RR);
}

__global__ void k_sumB(const float* __restrict__ code, float* __restrict__ B) {
  int k = blockIdx.x * 256 + threadIdx.x;
  B[k] = np_pw256_sq(code + (long)k * RR);
}

// ---------- K2a: fp16 MFMA single pass — m1, m2, argmin idx per row ----------
// v4: ct-loop unrolled x2 with named double-buffered b-fragments (bA/bB,
// static indexing) — loads for tile ct+1 issue while MFMAs consume tile ct,
// hiding the ~L2 latency that left ancestors at ~12% MfmaUtil / 80% stall.
// Arithmetic bit-identical: same loads, same MFMA chain, same min-track.
__global__ __launch_bounds__(256, 2)
void k_argmin(const float* __restrict__ z, const _Float16* __restrict__ cfs,
              const float* __restrict__ cnorm, float* __restrict__ m1arr,
              float* __restrict__ idxf, int* __restrict__ flagcnt,
              int* __restrict__ flags, int fcap) {
  __shared__ float sm1[4][64], sm2[4][64], si1[4][64];
  int n0 = blockIdx.x * 64;
  int tid = threadIdx.x;
  int l = tid & 63, w = tid >> 6;       // w = col-group 0..3
  int lr = l & 15, lg = l >> 4;

  half8 za[4][8];
#pragma unroll
  for (int rf = 0; rf < 4; ++rf) {
    const float* p = z + (long)(n0 + rf * 16 + lr) * RR + lg * 8;
#pragma unroll
    for (int ks = 0; ks < 8; ++ks) {
      f32x4 v0 = *(const f32x4*)(p + ks * 32);
      f32x4 v1 = *(const f32x4*)(p + ks * 32 + 4);
#pragma unroll
      for (int j = 0; j < 4; ++j) {
        za[rf][ks][j]     = (_Float16)v0[j];
        za[rf][ks][4 + j] = (_Float16)v1[j];
      }
    }
  }

  float m1[16], m2[16], i1[16];
#pragma unroll
  for (int s = 0; s < 16; ++s) { m1[s] = 3.4e38f; m2[s] = 3.4e38f; i1[s] = 0.f; }
  f32x4 zero = {0.f, 0.f, 0.f, 0.f};

  const _Float16* bbase = cfs + ((long)w << 12) + (l << 3);  // tile (ct*4+w)
  half8 bA[8], bB[8];
  // preload ct=0
#pragma unroll
  for (int ks = 0; ks < 8; ++ks) bA[ks] = *(const half8*)(bbase + ((long)ks << 9));

#define ARGMIN_STEP(CT, BCUR, BNXT, PREF)                                      \
  {                                                                            \
    if (PREF) {                                                                \
      const _Float16* bpn = bbase + ((long)((CT) + 1) << 14);                  \
      _Pragma("unroll")                                                        \
      for (int ks = 0; ks < 8; ++ks)                                           \
        BNXT[ks] = *(const half8*)(bpn + ((long)ks << 9));                     \
    }                                                                          \
    int col0 = (CT) * 64 + w * 16;                                             \
    float cn = cnorm[col0 + lr];                                               \
    float fi = (float)(col0 + lr);                                             \
    f32x4 a[4];                                                                \
    _Pragma("unroll")                                                          \
    for (int rf = 0; rf < 4; ++rf) a[rf] = zero;                               \
    _Pragma("unroll")                                                          \
    for (int ks = 0; ks < 8; ++ks) {                                           \
      _Pragma("unroll")                                                        \
      for (int rf = 0; rf < 4; ++rf)                                           \
        a[rf] = __builtin_amdgcn_mfma_f32_16x16x32_f16(za[rf][ks], BCUR[ks],   \
                                                       a[rf], 0, 0, 0);        \
    }                                                                          \
    _Pragma("unroll")                                                          \
    for (int rf = 0; rf < 4; ++rf)                                             \
      _Pragma("unroll")                                                        \
      for (int j = 0; j < 4; ++j) {                                            \
        int sl = rf * 4 + j;                                                   \
        float s = fmaf(-2.f, a[rf][j], cn);                                    \
        float om1 = m1[sl];                                                    \
        m2[sl] = fminf(m2[sl], fmaxf(s, om1));                                 \
        bool lt = s < om1;                                                     \
        m1[sl] = lt ? s : om1;                                                 \
        i1[sl] = lt ? fi : i1[sl];                                             \
      }                                                                        \
  }

  for (int ct = 0; ct < 126; ct += 2) {
    ARGMIN_STEP(ct, bA, bB, 1)
    ARGMIN_STEP(ct + 1, bB, bA, 1)
  }
  ARGMIN_STEP(126, bA, bB, 1)
  ARGMIN_STEP(127, bB, bA, 0)
#undef ARGMIN_STEP

  // 16-lane (candidate) reduce with first-index tie-break
#pragma unroll
  for (int sl = 0; sl < 16; ++sl) {
    float a1 = m1[sl], a2 = m2[sl], ai = i1[sl];
#pragma unroll
    for (int off = 1; off < 16; off <<= 1) {
      float b1 = __shfl_xor(a1, off);
      float b2 = __shfl_xor(a2, off);
      float bi = __shfl_xor(ai, off);
      float nm2 = fminf(fminf(a2, b2), fmaxf(a1, b1));
      bool take = (b1 < a1) || ((b1 == a1) && (bi < ai));
      a1 = take ? b1 : a1;
      ai = take ? bi : ai;
      a2 = nm2;
    }
    if (lr == 0) {
      int lrow = (sl >> 2) * 16 + lg * 4 + (sl & 3);
      sm1[w][lrow] = a1; sm2[w][lrow] = a2; si1[w][lrow] = ai;
    }
  }
  __syncthreads();
  if (tid < 64) {
    float a1 = sm1[0][tid], a2 = sm2[0][tid], ai = si1[0][tid];
#pragma unroll
    for (int ww = 1; ww < 4; ++ww) {
      float b1 = sm1[ww][tid], b2 = sm2[ww][tid], bi = si1[ww][tid];
      float nm2 = fminf(fminf(a2, b2), fmaxf(a1, b1));
      bool take = (b1 < a1) || ((b1 == a1) && (bi < ai));
      a1 = take ? b1 : a1;
      ai = take ? bi : ai;
      a2 = nm2;
    }
    int row = n0 + tid;
    idxf[row] = ai;
    m1arr[row] = a1;
    if (a2 - a1 < TAU_S) {
      int p = atomicAdd(flagcnt, 1);
      if (p < fcap) flags[p] = row;
    }
  }
}

// ---------- K2b: collect — FLAGGED ROWS ONLY, all candidates within TAU ----------
__global__ __launch_bounds__(256, 2)
void k_collect(const float* __restrict__ z, const _Float16* __restrict__ cfs,
               const float* __restrict__ cnorm, const float* __restrict__ m1arr,
               const int* __restrict__ flagcnt, const int* __restrict__ flags,
               int fcap, int* __restrict__ listcnt, unsigned* __restrict__ list,
               int cap) {
  int n = *flagcnt; if (n > fcap) n = fcap;
  int n0 = blockIdx.x * 64;
  if (n0 >= n) return;
  int tid = threadIdx.x;
  int l = tid & 63, w = tid >> 6;
  int lr = l & 15, lg = l >> 4;

  half8 za[4][8];
#pragma unroll
  for (int rf = 0; rf < 4; ++rf) {
    int fidx = n0 + rf * 16 + lr;
    int zrow = (fidx < n) ? flags[fidx] : 0;
    const float* p = z + (long)zrow * RR + lg * 8;
#pragma unroll
    for (int ks = 0; ks < 8; ++ks) {
      f32x4 v0 = *(const f32x4*)(p + ks * 32);
      f32x4 v1 = *(const f32x4*)(p + ks * 32 + 4);
#pragma unroll
      for (int j = 0; j < 4; ++j) {
        za[rf][ks][j]     = (_Float16)v0[j];
        za[rf][ks][4 + j] = (_Float16)v1[j];
      }
    }
  }

  unsigned rows[16];
  float thr[16];
#pragma unroll
  for (int sl = 0; sl < 16; ++sl) {
    int fidx = n0 + (sl >> 2) * 16 + lg * 4 + (sl & 3);
    bool v = fidx < n;
    rows[sl] = v ? (unsigned)flags[fidx] : 0u;
    thr[sl] = v ? m1arr[rows[sl]] + TAU_S : -3.4e38f;
  }
  f32x4 zero = {0.f, 0.f, 0.f, 0.f};

  for (int ct = 0; ct < 128; ++ct) {
    int col0 = ct * 64 + w * 16;
    int c16 = ct * 4 + w;
    const _Float16* bp = cfs + ((long)c16 << 12) + (l << 3);
    float cn = cnorm[col0 + lr];
    unsigned cand = (unsigned)(col0 + lr);
    f32x4 a[4];
#pragma unroll
    for (int rf = 0; rf < 4; ++rf) a[rf] = zero;
#pragma unroll
    for (int ks = 0; ks < 8; ++ks) {
      half8 b = *(const half8*)(bp + ((long)ks << 9));
#pragma unroll
      for (int rf = 0; rf < 4; ++rf)
        a[rf] = __builtin_amdgcn_mfma_f32_16x16x32_f16(za[rf][ks], b, a[rf], 0, 0, 0);
    }
#pragma unroll
    for (int rf = 0; rf < 4; ++rf)
#pragma unroll
      for (int j = 0; j < 4; ++j) {
        int sl = rf * 4 + j;
        float s = fmaf(-2.f, a[rf][j], cn);
        if (s < thr[sl]) {
          int pos = atomicAdd(listcnt, 1);
          if (pos < cap) list[pos] = (rows[sl] << 13) | cand;
        }
      }
  }
}

// ---------- K2c: np-replica d2 for shortlist; packed-key argmin ----------
__global__ void k_npd2(const float* __restrict__ z, const float* __restrict__ code,
                       const float* __restrict__ A, const float* __restrict__ B,
                       const int* __restrict__ listcnt, const unsigned* __restrict__ list,
                       unsigned long long* __restrict__ keys, int cap) {
#pragma clang fp contract(off)
  int n = *listcnt; if (n > cap) n = cap;
  for (int i = blockIdx.x * 256 + threadIdx.x; i < n; i += gridDim.x * 256) {
    unsigned e = list[i];
    int row = (int)(e >> 13), k = (int)(e & 8191u);
    const float* zp = z + (long)row * RR;
    const float* cp = code + (long)k * RR;
    float s0 = 0.f, s1 = 0.f, s2 = 0.f, s3 = 0.f;
    for (int g = 0; g < 64; ++g) {
      f32x4 zv = *(const f32x4*)(zp + g * 4);
      f32x4 cv = *(const f32x4*)(cp + g * 4);
      s0 = s0 + zv[0] * cv[0];
      s1 = s1 + zv[1] * cv[1];
      s2 = s2 + zv[2] * cv[2];
      s3 = s3 + zv[3] * cv[3];
    }
    float C = (s0 + s1) + (s2 + s3);
    float t1 = A[row] + B[k];
    float d2 = t1 - 2.0f * C;
    unsigned long long key = ((unsigned long long)__float_as_uint(d2) << 13) |
                             (unsigned long long)(unsigned)k;
    atomicMin(&keys[row], key);
  }
}

// ---------- K2d: overwrite idx for flagged rows from np-fp32 keys ----------
__global__ void k_fix(const int* __restrict__ flagcnt, const int* __restrict__ flags,
                      const unsigned long long* __restrict__ keys,
                      float* __restrict__ idxf, int fcap) {
  int n = *flagcnt; if (n > fcap) n = fcap;
  for (int i = blockIdx.x * 256 + threadIdx.x; i < n; i += gridDim.x * 256) {
    int row = flags[i];
    unsigned long long k = keys[row];
    if (k != ~0ULL) idxf[row] = (float)(unsigned)(k & 8191ULL);
  }
}

// ---------- K3a: q = code[idx], cb partial sums ----------
__global__ void k_gather(const float* __restrict__ code, const float* __restrict__ z,
                         const float* __restrict__ idxf, float* __restrict__ q,
                         float* __restrict__ cbsum) {
  int t = threadIdx.x;
  int rid = blockIdx.x * 4 + (t >> 6);
  int l = t & 63;
  int k = (int)idxf[rid];
  f32x4 cv = ((const f32x4*)code)[(long)k * 64 + l];
  f32x4 zv = ((const f32x4*)z)[(long)rid * 64 + l];
  ((f32x4*)q)[(long)rid * 64 + l] = cv;
  f32x4 d = cv - zv;
  float s = d[0]*d[0] + d[1]*d[1] + d[2]*d[2] + d[3]*d[3];
#pragma unroll
  for (int off = 1; off < 64; off <<= 1) s += __shfl_xor(s, off);
  __shared__ float sw[4];
  if (l == 0) sw[t >> 6] = s;
  __syncthreads();
  if (t == 0) atomicAdd(cbsum, sw[0] + sw[1] + sw[2] + sw[3]);
}

// ---------- K3b: rec = mean((q@W - x)^2), fused fp16 MFMA + reduction ----------
__global__ __launch_bounds__(512, 2)
void k_rec(const float* __restrict__ q, const _Float16* __restrict__ Wt,
           const float* __restrict__ x, float* __restrict__ recsum) {
  int n0 = blockIdx.x * 128;
  int d0 = blockIdx.y * 512;
  int tid = threadIdx.x;
  int l = tid & 63, w = tid >> 6;
  int wr = w >> 2, wc = w & 3;
  int lr = l & 15, lg = l >> 4;
  f32x4 zero = {0.f, 0.f, 0.f, 0.f};
  f32x4 acc[4][8];
#pragma unroll
  for (int a = 0; a < 4; ++a)
#pragma unroll
    for (int b = 0; b < 8; ++b) acc[a][b] = zero;

  for (int kk = 0; kk < 8; ++kk) {
    half8 aq[4];
#pragma unroll
    for (int rf = 0; rf < 4; ++rf) {
      const float* p = q + (long)(n0 + wr * 64 + rf * 16 + lr) * RR + kk * 32 + lg * 8;
      f32x4 v0 = *(const f32x4*)p;
      f32x4 v1 = *(const f32x4*)(p + 4);
#pragma unroll
      for (int j = 0; j < 4; ++j) {
        aq[rf][j]     = (_Float16)v0[j];
        aq[rf][4 + j] = (_Float16)v1[j];
      }
    }
#pragma unroll
    for (int cfg = 0; cfg < 8; ++cfg) {
      const _Float16* bp = Wt + (long)(d0 + wc * 128 + cfg * 16 + lr) * RR + kk * 32 + lg * 8;
      half8 b = *(const half8*)bp;
#pragma unroll
      for (int rf = 0; rf < 4; ++rf)
        acc[rf][cfg] = __builtin_amdgcn_mfma_f32_16x16x32_f16(aq[rf], b, acc[rf][cfg], 0, 0, 0);
    }
  }
  float s = 0.f;
#pragma unroll
  for (int rf = 0; rf < 4; ++rf)
#pragma unroll
    for (int cfg = 0; cfg < 8; ++cfg)
#pragma unroll
      for (int j = 0; j < 4; ++j) {
        int n = n0 + wr * 64 + rf * 16 + lg * 4 + j;
        int d = d0 + wc * 128 + cfg * 16 + lr;
        float df = acc[rf][cfg][j] - x[(long)n * DD + d];
        s = fmaf(df, df, s);
      }
#pragma unroll
  for (int off = 1; off < 64; off <<= 1) s += __shfl_xor(s, off);
  __shared__ float sw[8];
  if (l == 0) sw[w] = s;
  __syncthreads();
  if (tid == 0) {
    float t8 = 0.f;
#pragma unroll
    for (int i = 0; i < 8; ++i) t8 += sw[i];
    atomicAdd(recsum, t8);
  }
}

// ---------- K3c: scalars ----------
__global__ void k_final(const float* __restrict__ rs, const float* __restrict__ cbs,
                        float* __restrict__ out) {
  if (threadIdx.x == 0 && blockIdx.x == 0) {
    float rec = *rs * (1.0f / 33554432.0f);   // / (N*D)
    float cb  = *cbs * (1.0f / 8388608.0f);   // / (N*R)
    out[0] = rec + 1.25f * cb;                // rec + cb + BETA*cb
    out[1] = rec;
  }
}

extern "C" void kernel_launch(void* const* d_in, const int* in_sizes, int n_in,
                              void* d_out, int out_size, void* d_ws, size_t ws_size,
                              hipStream_t stream) {
  (void)in_sizes; (void)n_in; (void)out_size; (void)ws_size;
  const float* x    = (const float*)d_in[0];
  const float* W    = (const float*)d_in[1];
  const float* code = (const float*)d_in[2];
  float* out = (float*)d_out;
  char* ws = (char*)d_ws;

  _Float16* Wt = (_Float16*)(ws + O_WT);
  _Float16* cfs = (_Float16*)(ws + O_CF);
  float* cnorm = (float*)(ws + O_CN);
  float* A = (float*)(ws + O_A);
  float* B = (float*)(ws + O_B);
  float* m1arr = (float*)(ws + O_M1);
  unsigned long long* keys = (unsigned long long*)(ws + O_KEY);
  int* listcnt = (int*)(ws + O_CNT);
  int* flagcnt = (int*)(ws + O_CNT + 4);
  float* recsum = (float*)(ws + O_CNT + 8);
  float* cbsum  = (float*)(ws + O_CNT + 12);
  int* flags = (int*)(ws + O_FLAG);
  unsigned* list = (unsigned*)(ws + O_LIST);

  float* zp = out + OFF_Z;
  float* qp = out + OFF_Q;
  float* ip = out + OFF_IDX;

  hipMemsetAsync(ws + O_CNT, 0, 16, stream);
  hipMemsetAsync(ws + O_KEY, 0xFF, (size_t)NN * 8, stream);

  k_wt<<<dim3(16, 4), dim3(256), 0, stream>>>(W, Wt);
  k_code<<<dim3(KK), dim3(64), 0, stream>>>(code, cfs, cnorm);
  k_npz<<<dim3(1024, 2), dim3(256), 0, stream>>>(x, W, zp);
  k_sumA<<<dim3(128), dim3(256), 0, stream>>>(zp, A);
  k_sumB<<<dim3(32), dim3(256), 0, stream>>>(code, B);
  k_argmin<<<dim3(512), dim3(256), 0, stream>>>(zp, cfs, cnorm, m1arr, ip, flagcnt, flags, FCAP);
  k_collect<<<dim3(FCAP / 64), dim3(256), 0, stream>>>(zp, cfs, cnorm, m1arr, flagcnt, flags, FCAP, listcnt, list, LIST_CAP);
  k_npd2<<<dim3(256), dim3(256), 0, stream>>>(zp, code, A, B, listcnt, list, keys, LIST_CAP);
  k_fix<<<dim3(64), dim3(256), 0, stream>>>(flagcnt, flags, keys, ip, FCAP);
  k_gather<<<dim3(8192), dim3(256), 0, stream>>>(code, zp, ip, qp, cbsum);
  k_rec<<<dim3(256, 2), dim3(512), 0, stream>>>(qp, Wt, x, recsum);
  k_final<<<dim3(1), dim3(64), 0, stream>>>(recsum, cbsum, out);
}